// Round 10
// baseline (64.264 us; speedup 1.0000x reference)
//
#include <hip/hip_runtime.h>

#define IMG 512
#define TW 64
#define TH 32
#define GROWS 38   // GH row k = image row ty0-3+k
#define PROWS 42   // HN/HX row r = image row ty0-5+r

typedef unsigned short u16t;

__device__ __forceinline__ float nan0(float v){ return v==v ? v : 0.0f; }
__device__ __forceinline__ float min3f(float a,float b,float c){ return fminf(fminf(a,b),c); }
__device__ __forceinline__ float max3f(float a,float b,float c){ return fmaxf(fmaxf(a,b),c); }
// bf16 via bit truncation: deterministic, 1-3 ops, NaN(0x7FC00000) survives.
__device__ __forceinline__ unsigned pk2(float lo, float hi){
    return (__float_as_uint(hi) & 0xFFFF0000u) | (__float_as_uint(lo) >> 16);
}
__device__ __forceinline__ float up16(u16t u){
    return __uint_as_float(((unsigned)u) << 16);
}

__global__ __launch_bounds__(256)
void simplenet_fused(const float* __restrict__ X,
                     const float* __restrict__ w0, const float* __restrict__ b0,
                     const float* __restrict__ w1, const float* __restrict__ w2,
                     const float* __restrict__ w3, const float* __restrict__ w4,
                     const float* __restrict__ w5, const float* __restrict__ w6,
                     float* __restrict__ out)
{
    // Exchange planes only, stored bf16 (truncated): 15616 B -> 8-block LDS cap.
    __shared__ u16t GH[GROWS*64];   // 4864 B gaussH
    __shared__ u16t HN[PROWS*64];   // 5376 B h11 min
    __shared__ u16t HX[PROWS*64];   // 5376 B h11 max

    const int tid = threadIdx.x;
    const int xo = tid & 63, ty = tid >> 6, y0 = ty*8;   // 8 consecutive rows/thread
    const int bx = blockIdx.x, by = blockIdx.y, bz = blockIdx.z;
    const int tx0 = bx*TW, ty0 = by*TH;
    const bool xe = (bx==0)||(bx==IMG/TW-1);
    const bool ye = (by==0)||(by==IMG/TH-1);
    const float* Xb = X + (size_t)bz*(IMG*IMG);
    const float qn = __builtin_nanf("");

    const float W0c0=w0[0], W0c1=w0[1], B0=b0[0], B1=b0[1];
    const float W1c0=w1[0], W1c1=w1[1], W2c0=w2[0], W2c1=w2[1];
    const float W3c0=w3[0], W3c1=w3[1], W4c0=w4[0], W4c1=w4[1];
    const float W5c0=w5[0], W5c1=w5[1], W6c0=w6[0], W6c1=w6[1];

    const float G0=0.10628875f, G1=0.14032194f, G2=0.16577342f, G3=0.17523179f;

    // ---- producers: 42 rows x 8 col-tasks (8 outputs each); global->regs->LDS ----
    for (int t = tid; t < PROWS*8; t += 256) {
        const int r = t >> 3, g = t & 7;
        const int gy  = ty0 - 5 + r;
        const int gx0 = tx0 + 8*g - 8;          // x[i] <-> global col gx0+i
        float x[28];
        const bool yv = !ye || ((unsigned)gy < IMG);
        if (yv) {
            if (!xe) {
#pragma unroll
                for (int j=0;j<7;++j) {
                    const float4 q = *(const float4*)(Xb + gy*IMG + gx0 + 4*j);
                    x[4*j]=q.x; x[4*j+1]=q.y; x[4*j+2]=q.z; x[4*j+3]=q.w;
                }
            } else {
                const float* row = Xb + gy*IMG;
#pragma unroll
                for (int i=0;i<28;++i) {
                    const int gx = gx0 + i;
                    const float v = row[min(max(gx,0),IMG-1)];
                    x[i] = ((unsigned)gx < IMG) ? v : qn;
                }
            }
        } else {
#pragma unroll
            for (int i=0;i<28;++i) x[i] = qn;
        }
        // 3-wide running min/max, center x[i+4], i=0..15
        float mn[16], mx[16];
#pragma unroll
        for (int i=0;i<16;++i) {
            mn[i] = min3f(x[i+3],x[i+4],x[i+5]);
            mx[i] = max3f(x[i+3],x[i+4],x[i+5]);
        }
        // h11 for outputs k=0..7 (window x[k+3..k+13]) = m3 at offsets {0,3,6,8}
        float hn8[8], hx8[8];
#pragma unroll
        for (int k=0;k<8;++k) {
            hn8[k] = fminf(fminf(mn[k],mn[k+3]), fminf(mn[k+6],mn[k+8]));
            hx8[k] = fmaxf(fmaxf(mx[k],mx[k+3]), fmaxf(mx[k+6],mx[k+8]));
        }
        uint4 qn4, qx4;
        qn4.x = pk2(hn8[0],hn8[1]); qn4.y = pk2(hn8[2],hn8[3]);
        qn4.z = pk2(hn8[4],hn8[5]); qn4.w = pk2(hn8[6],hn8[7]);
        qx4.x = pk2(hx8[0],hx8[1]); qx4.y = pk2(hx8[2],hx8[3]);
        qx4.z = pk2(hx8[4],hx8[5]); qx4.w = pk2(hx8[6],hx8[7]);
        *(uint4*)&HN[r*64+8*g] = qn4;
        *(uint4*)&HX[r*64+8*g] = qx4;
        if (r >= 2 && r < 40) {                 // gaussH only for rows the v-window uses
            float zz[14];
#pragma unroll
            for (int j=0;j<14;++j) zz[j] = xe ? nan0(x[5+j]) : x[5+j];
            float gh8[8];
#pragma unroll
            for (int k=0;k<8;++k)
                gh8[k] = G0*(zz[k]+zz[k+6]) + G1*(zz[k+1]+zz[k+5]) + G2*(zz[k+2]+zz[k+4]) + G3*zz[k+3];
            uint4 qg;
            qg.x = pk2(gh8[0],gh8[1]); qg.y = pk2(gh8[2],gh8[3]);
            qg.z = pk2(gh8[4],gh8[5]); qg.w = pk2(gh8[6],gh8[7]);
            *(uint4*)&GH[(r-2)*64+8*g] = qg;
        }
    }

    float a0[8], a1[8];

    // ---- trio (identity + 3x3 cross + pool3) straight from global/L1 ----
    {
        const int gxc = tx0 + xo;
        float L[10], C[10], R[10];
        if (!xe && !ye) {
#pragma unroll
            for (int i=0;i<10;++i) {
                const float* row = Xb + (ty0+y0-1+i)*IMG + gxc;
                L[i]=row[-1]; C[i]=row[0]; R[i]=row[1];
            }
        } else {
#pragma unroll
            for (int i=0;i<10;++i) {
                const int gy = ty0+y0-1+i;
                const bool yv = (unsigned)gy < IMG;
                const float* row = Xb + (yv ? gy : 0)*IMG;
                float l = row[max(gxc-1,0)], c = row[gxc], r = row[min(gxc+1,IMG-1)];
                if (!yv) { l=qn; c=qn; r=qn; }
                if (gxc==0)     l=qn;
                if (gxc==IMG-1) r=qn;
                L[i]=l; C[i]=c; R[i]=r;
            }
        }
        float hm[10], hx10[10];
#pragma unroll
        for (int i=0;i<10;++i) { hm[i]=min3f(L[i],C[i],R[i]); hx10[i]=max3f(L[i],C[i],R[i]); }
        float Lz[10], Rz[10];
#pragma unroll
        for (int i=0;i<10;++i) { Lz[i] = xe ? nan0(L[i]) : L[i];
                                 Rz[i] = xe ? nan0(R[i]) : R[i]; }
        const float Cz0 = ye ? nan0(C[0]) : C[0];
        const float Cz9 = ye ? nan0(C[9]) : C[9];
#pragma unroll
        for (int p=0;p<8;++p) {
            const float up = (p==0) ? Cz0 : C[p];
            const float dn = (p==7) ? Cz9 : C[p+2];
            const float cr = 0.25f*(up + dn + Lz[p+1] + Rz[p+1]);
            a0[p] = B0 + W0c0*C[p+1] + W1c0*cr;
            a1[p] = B1 + W0c1*C[p+1] + W1c1*cr;
            const float mnv = min3f(hm[p],hm[p+1],hm[p+2]);
            const float mxv = max3f(hx10[p],hx10[p+1],hx10[p+2]);
            a0[p] += W3c0*mnv + W5c0*mxv;
            a1[p] += W3c1*mnv + W5c1*mxv;
        }
    }
    __syncthreads();

    // ---- gaussV: 14 bf16 column reads -> 8 outputs ----
    {
        float wv[14];
#pragma unroll
        for (int i=0;i<14;++i) wv[i] = up16(GH[(y0+i)*64+xo]);
        if (ye) {
#pragma unroll
            for (int i=0;i<14;++i) wv[i] = nan0(wv[i]);
        }
#pragma unroll
        for (int p=0;p<8;++p) {
            const float s = G0*(wv[p]+wv[p+6]) + G1*(wv[p+1]+wv[p+5])
                          + G2*(wv[p+2]+wv[p+4]) + G3*wv[p+3];
            a0[p] += W2c0*s; a1[p] += W2c1*s;
        }
    }

    // ---- v11 van Herk over 18 bf16 rows -> 8 outputs ----
    {
        float hn[18], hx[18];
#pragma unroll
        for (int i=0;i<18;++i) { hn[i]=up16(HN[(y0+i)*64+xo]); hx[i]=up16(HX[(y0+i)*64+xo]); }
        float sn[11], sx[11];
        sn[10]=hn[10]; sx[10]=hx[10];
#pragma unroll
        for (int i=9;i>=0;--i) { sn[i]=fminf(hn[i],sn[i+1]); sx[i]=fmaxf(hx[i],sx[i+1]); }
        a0[0] += W4c0*sn[0] + W6c0*sx[0];
        a1[0] += W4c1*sn[0] + W6c1*sx[0];
        float pn = hn[11], px = hx[11];
#pragma unroll
        for (int p=1;p<8;++p) {
            const float on = fminf(sn[p], pn);
            const float ox = fmaxf(sx[p], px);
            a0[p] += W4c0*on + W6c0*ox;
            a1[p] += W4c1*on + W6c1*ox;
            if (p<7) { pn = fminf(pn, hn[p+11]); px = fmaxf(px, hx[p+11]); }
        }
    }

    float* o0p = out + ((size_t)bz*2 + 0)*(IMG*IMG) + (size_t)(ty0+y0)*IMG + tx0 + xo;
    float* o1p = o0p + (IMG*IMG);
#pragma unroll
    for (int p=0;p<8;++p) {
        o0p[(size_t)p*IMG] = a0[p];
        o1p[(size_t)p*IMG] = a1[p];
    }
}

extern "C" void kernel_launch(void* const* d_in, const int* in_sizes, int n_in,
                              void* d_out, int out_size, void* d_ws, size_t ws_size,
                              hipStream_t stream) {
    const float* X  = (const float*)d_in[0];
    const float* w0 = (const float*)d_in[1];
    const float* b0 = (const float*)d_in[2];
    const float* w1 = (const float*)d_in[3];
    const float* w2 = (const float*)d_in[4];
    const float* w3 = (const float*)d_in[5];
    const float* w4 = (const float*)d_in[6];
    const float* w5 = (const float*)d_in[7];
    const float* w6 = (const float*)d_in[8];
    float* out = (float*)d_out;

    dim3 grid(IMG/TW, IMG/TH, 32);
    simplenet_fused<<<grid, 256, 0, stream>>>(X, w0, b0, w1, w2, w3, w4, w5, w6, out);
}

// Round 11
// 45.498 us; speedup vs baseline: 1.4125x; 1.4125x over previous
//
#include <hip/hip_runtime.h>

#define IMG 512
#define TW 64
#define TH 16
#define GST 64     // plane stride (elements)

__device__ __forceinline__ float nan0(float v){ return v==v ? v : 0.0f; }
__device__ __forceinline__ float min3f(float a,float b,float c){ return fminf(fminf(a,b),c); }
__device__ __forceinline__ float max3f(float a,float b,float c){ return fmaxf(fmaxf(a,b),c); }
// bf16 pair pack: lo in low16 (>>16), hi in high16. Truncation is monotone ->
// commutes with min/max; NaN 0x7FC00000 -> 0x7FC0 survives both halves.
__device__ __forceinline__ unsigned pk2(float lo, float hi){
    return (__float_as_uint(hi) & 0xFFFF0000u) | (__float_as_uint(lo) >> 16);
}
__device__ __forceinline__ float up_lo(unsigned u){ return __uint_as_float(u << 16); }
__device__ __forceinline__ float up_hi(unsigned u){ return __uint_as_float(u & 0xFFFF0000u); }

__global__ __launch_bounds__(256)
void simplenet_fused(const float* __restrict__ X,
                     const float* __restrict__ w0, const float* __restrict__ b0,
                     const float* __restrict__ w1, const float* __restrict__ w2,
                     const float* __restrict__ w3, const float* __restrict__ w4,
                     const float* __restrict__ w5, const float* __restrict__ w6,
                     float* __restrict__ out)
{
    // Exchange planes only; raw pixels re-read from global (L1-resident tile).
    __shared__ float    GH [22*GST];  // 5632 B gaussH f32; row k = image row ty0-3+k
    __shared__ unsigned HNX[26*GST];  // 6656 B (h11min,h11max) bf16 pairs; row r = ty0-5+r

    const int tid = threadIdx.x;
    const int xo = tid & 63, ty = tid >> 6, y0 = ty*4;   // 4 consecutive rows/thread
    const int bx = blockIdx.x, by = blockIdx.y, bz = blockIdx.z;
    const int tx0 = bx*TW, ty0 = by*TH;
    const bool xe = (bx==0)||(bx==IMG/TW-1);
    const bool ye = (by==0)||(by==IMG/TH-1);
    const float* Xb = X + (size_t)bz*(IMG*IMG);
    const float qn = __builtin_nanf("");

    const float W0c0=w0[0], W0c1=w0[1], B0=b0[0], B1=b0[1];
    const float W1c0=w1[0], W1c1=w1[1], W2c0=w2[0], W2c1=w2[1];
    const float W3c0=w3[0], W3c1=w3[1], W4c0=w4[0], W4c1=w4[1];
    const float W5c0=w5[0], W5c1=w5[1], W6c0=w6[0], W6c1=w6[1];

    const float G0=0.10628875f, G1=0.14032194f, G2=0.16577342f, G3=0.17523179f;

    // ---- producers: 26 rows x 16 col-tasks; global->regs->LDS ----
    for (int t = tid; t < 26*16; t += 256) {
        const int r = t >> 4, g = t & 15;
        const int gy  = ty0 - 5 + r;
        const int gx0 = tx0 - 8 + 4*g;          // x[i] <-> global col gx0+i
        float x[20];
        const bool yv = !ye || ((unsigned)gy < IMG);
        if (yv) {
            if (!xe) {
#pragma unroll
                for (int j=0;j<5;++j) {
                    const float4 q = *(const float4*)(Xb + gy*IMG + gx0 + 4*j);
                    x[4*j]=q.x; x[4*j+1]=q.y; x[4*j+2]=q.z; x[4*j+3]=q.w;
                }
            } else {
                const float* row = Xb + gy*IMG;
#pragma unroll
                for (int j=0;j<5;++j) {
                    const int c0 = gx0 + 4*j;
                    if (c0 >= 0 && c0 + 3 < IMG) {
                        const float4 q = *(const float4*)(row + c0);
                        x[4*j]=q.x; x[4*j+1]=q.y; x[4*j+2]=q.z; x[4*j+3]=q.w;
                    } else {
#pragma unroll
                        for (int i=0;i<4;++i) {
                            const int gx = c0 + i;
                            const float v = row[min(max(gx,0),IMG-1)];
                            x[4*j+i] = ((unsigned)gx < IMG) ? v : qn;
                        }
                    }
                }
            }
        } else {
#pragma unroll
            for (int i=0;i<20;++i) x[i] = qn;
        }
        // 3-wide running min/max, center x[i+4]
        float mn[12], mx[12];
#pragma unroll
        for (int i=0;i<12;++i) {
            mn[i] = min3f(x[i+3],x[i+4],x[i+5]);
            mx[i] = max3f(x[i+3],x[i+4],x[i+5]);
        }
        unsigned hw[4];
#pragma unroll
        for (int k=0;k<4;++k) {                 // 11-window = m3 at offsets 0,3,6,8
            const float hn = fminf(fminf(mn[k],mn[k+3]), fminf(mn[k+6],mn[k+8]));
            const float hx = fmaxf(fmaxf(mx[k],mx[k+3]), fmaxf(mx[k+6],mx[k+8]));
            hw[k] = pk2(hn, hx);
        }
        *(uint4*)&HNX[r*GST+4*g] = make_uint4(hw[0],hw[1],hw[2],hw[3]);
        if (r >= 2 && r < 24) {                 // gaussH only for rows the v-window uses
            float zz[10];
#pragma unroll
            for (int j=0;j<10;++j) zz[j] = xe ? nan0(x[5+j]) : x[5+j];
            float gh4[4];
#pragma unroll
            for (int k=0;k<4;++k)
                gh4[k] = G0*(zz[k]+zz[k+6]) + G1*(zz[k+1]+zz[k+5]) + G2*(zz[k+2]+zz[k+4]) + G3*zz[k+3];
            *(float4*)&GH[(r-2)*GST+4*g] = make_float4(gh4[0],gh4[1],gh4[2],gh4[3]);
        }
    }

    float a0[4], a1[4];

    // ---- trio (identity + 3x3 cross + pool3) straight from global/L1 ----
    {
        const int gxc = tx0 + xo;
        float L[6], C[6], R[6];
        if (!xe && !ye) {
#pragma unroll
            for (int i=0;i<6;++i) {
                const float* row = Xb + (ty0+y0-1+i)*IMG + gxc;
                L[i]=row[-1]; C[i]=row[0]; R[i]=row[1];
            }
        } else {
#pragma unroll
            for (int i=0;i<6;++i) {
                const int gy = ty0+y0-1+i;
                const bool yv = (unsigned)gy < IMG;
                const float* row = Xb + (yv ? gy : 0)*IMG;
                float l = row[max(gxc-1,0)], c = row[gxc], r = row[min(gxc+1,IMG-1)];
                if (!yv) { l=qn; c=qn; r=qn; }
                if (gxc==0)     l=qn;
                if (gxc==IMG-1) r=qn;
                L[i]=l; C[i]=c; R[i]=r;
            }
        }
        float hm[6], hx6[6];
#pragma unroll
        for (int i=0;i<6;++i) { hm[i]=min3f(L[i],C[i],R[i]); hx6[i]=max3f(L[i],C[i],R[i]); }
        float Lz[6], Rz[6];
#pragma unroll
        for (int i=0;i<6;++i) { Lz[i] = xe ? nan0(L[i]) : L[i];
                                Rz[i] = xe ? nan0(R[i]) : R[i]; }
        const float Cz0 = ye ? nan0(C[0]) : C[0];
        const float Cz5 = ye ? nan0(C[5]) : C[5];
        const float up[4]={Cz0,C[1],C[2],C[3]};
        const float dn[4]={C[2],C[3],C[4],Cz5};
#pragma unroll
        for (int p=0;p<4;++p) {
            const float cr = 0.25f*(up[p] + dn[p] + Lz[p+1] + Rz[p+1]);
            a0[p] = B0 + W0c0*C[p+1] + W1c0*cr;
            a1[p] = B1 + W0c1*C[p+1] + W1c1*cr;
            const float mnv = min3f(hm[p],hm[p+1],hm[p+2]);
            const float mxv = max3f(hx6[p],hx6[p+1],hx6[p+2]);
            a0[p] += W3c0*mnv + W5c0*mxv;
            a1[p] += W3c1*mnv + W5c1*mxv;
        }
    }
    __syncthreads();

    // ---- consumers: batch ALL LDS loads first (10 GH + 14 HNX) for ILP ----
    {
        float wv[10];
        unsigned q[14];
#pragma unroll
        for (int i=0;i<10;++i) wv[i] = GH[(y0+i)*GST+xo];
#pragma unroll
        for (int i=0;i<14;++i) q[i]  = HNX[(y0+i)*GST+xo];
        if (ye) {
#pragma unroll
            for (int i=0;i<10;++i) wv[i] = nan0(wv[i]);
        }
        // gaussV
#pragma unroll
        for (int p=0;p<4;++p) {
            const float s = G0*(wv[p]+wv[p+6]) + G1*(wv[p+1]+wv[p+5])
                          + G2*(wv[p+2]+wv[p+4]) + G3*wv[p+3];
            a0[p] += W2c0*s; a1[p] += W2c1*s;
        }
        // v11 van Herk over 14 bf16-pair rows
        float hn[14], hx[14];
#pragma unroll
        for (int i=0;i<14;++i) { hn[i]=up_lo(q[i]); hx[i]=up_hi(q[i]); }
        float an = hn[10], ax = hx[10];
#pragma unroll
        for (int i=9;i>=4;--i) { an=fminf(an,hn[i]); ax=fmaxf(ax,hx[i]); }
        const float Sn3=fminf(an,hn[3]),  Sx3=fmaxf(ax,hx[3]);
        const float Sn2=fminf(Sn3,hn[2]), Sx2=fmaxf(Sx3,hx[2]);
        const float Sn1=fminf(Sn2,hn[1]), Sx1=fmaxf(Sx2,hx[1]);
        const float Sn0=fminf(Sn1,hn[0]), Sx0=fmaxf(Sx1,hx[0]);
        const float pn1=hn[11],            px1=hx[11];
        const float pn2=fminf(pn1,hn[12]), px2=fmaxf(px1,hx[12]);
        const float pn3=fminf(pn2,hn[13]), px3=fmaxf(px2,hx[13]);
        const float on[4]={Sn0, fminf(Sn1,pn1), fminf(Sn2,pn2), fminf(Sn3,pn3)};
        const float ox[4]={Sx0, fmaxf(Sx1,px1), fmaxf(Sx2,px2), fmaxf(Sx3,px3)};
#pragma unroll
        for (int p=0;p<4;++p) {
            a0[p]+=W4c0*on[p]+W6c0*ox[p];
            a1[p]+=W4c1*on[p]+W6c1*ox[p];
        }
    }

    float* o0p = out + ((size_t)bz*2 + 0)*(IMG*IMG) + (size_t)(ty0+y0)*IMG + tx0 + xo;
    float* o1p = o0p + (IMG*IMG);
#pragma unroll
    for (int p=0;p<4;++p) {
        o0p[(size_t)p*IMG] = a0[p];
        o1p[(size_t)p*IMG] = a1[p];
    }
}

extern "C" void kernel_launch(void* const* d_in, const int* in_sizes, int n_in,
                              void* d_out, int out_size, void* d_ws, size_t ws_size,
                              hipStream_t stream) {
    const float* X  = (const float*)d_in[0];
    const float* w0 = (const float*)d_in[1];
    const float* b0 = (const float*)d_in[2];
    const float* w1 = (const float*)d_in[3];
    const float* w2 = (const float*)d_in[4];
    const float* w3 = (const float*)d_in[5];
    const float* w4 = (const float*)d_in[6];
    const float* w5 = (const float*)d_in[7];
    const float* w6 = (const float*)d_in[8];
    float* out = (float*)d_out;

    dim3 grid(IMG/TW, IMG/TH, 32);
    simplenet_fused<<<grid, 256, 0, stream>>>(X, w0, b0, w1, w2, w3, w4, w5, w6, out);
}

// Round 13
// 39.079 us; speedup vs baseline: 1.6445x; 1.1643x over previous
//
#include <hip/hip_runtime.h>

#define IMG 512
#define TW 64
#define TH 32
#define GROWS 38   // GH row k = image row ty0-3+k
#define PROWS 42   // HNX row r = image row ty0-5+r
#define GST 64     // plane stride (elements)

typedef __fp16 h2v __attribute__((ext_vector_type(2)));
union UH { unsigned u; h2v h; };

__device__ __forceinline__ float nan0(float v){ return v==v ? v : 0.0f; }
__device__ __forceinline__ float min3f(float a,float b,float c){ return fminf(fminf(a,b),c); }
__device__ __forceinline__ float max3f(float a,float b,float c){ return fmaxf(fmaxf(a,b),c); }

__global__ __launch_bounds__(512)
void simplenet_fused(const float* __restrict__ X,
                     const float* __restrict__ w0, const float* __restrict__ b0,
                     const float* __restrict__ w1, const float* __restrict__ w2,
                     const float* __restrict__ w3, const float* __restrict__ w4,
                     const float* __restrict__ w5, const float* __restrict__ w6,
                     float* __restrict__ out)
{
    // Exchange planes only; raw pixels re-read from global (L1-resident tile).
    // HNX holds f16 pairs (h11min, -h11max): one v_pk_min_f16 advances BOTH
    // pool chains. f16 path is NaN-free by construction (sentinels are +65504).
    __shared__ float    GH [GROWS*GST];   //  9728 B gaussH f32
    __shared__ unsigned HNX[PROWS*GST];   // 10752 B packed f16 pairs

    const int tid = threadIdx.x;
    const int xo = tid & 63, ty = tid >> 6, y0 = ty*4;   // ty 0..7, 4 rows/thread
    const int bx = blockIdx.x, by = blockIdx.y, bz = blockIdx.z;
    const int tx0 = bx*TW, ty0 = by*TH;
    const bool xe = (bx==0)||(bx==IMG/TW-1);
    const bool ye = (by==0)||(by==IMG/TH-1);
    const float* Xb = X + (size_t)bz*(IMG*IMG);
    const float qn = __builtin_nanf("");

    const float W0c0=w0[0], W0c1=w0[1], B0=b0[0], B1=b0[1];
    const float W1c0=w1[0], W1c1=w1[1], W2c0=w2[0], W2c1=w2[1];
    const float W3c0=w3[0], W3c1=w3[1], W4c0=w4[0], W4c1=w4[1];
    const float W5c0=w5[0], W5c1=w5[1], W6c0=w6[0], W6c1=w6[1];

    const float G0=0.10628875f, G1=0.14032194f, G2=0.16577342f, G3=0.17523179f;

    // ---- producers: 42 rows x 16 col-tasks = 672 tasks over 512 threads ----
    for (int t = tid; t < PROWS*16; t += 512) {
        const int r = t >> 4, g = t & 15;
        const int gy  = ty0 - 5 + r;
        const int gx0 = tx0 - 8 + 4*g;          // x[i] <-> global col gx0+i
        const int wb  = r*GST + 4*g;
        if ((unsigned)gy >= IMG) {              // fully OOB row: sentinels
            *(uint4*)&HNX[wb] = make_uint4(0x7BFF7BFFu,0x7BFF7BFFu,0x7BFF7BFFu,0x7BFF7BFFu);
            if (r >= 2 && r < 40)
                *(float4*)&GH[(r-2)*GST+4*g] = make_float4(qn,qn,qn,qn);
            continue;
        }
        float x[20];
        const bool xs = (unsigned)gx0 > (unsigned)(IMG-20);  // edge task (rare)
        if (!xs) {
#pragma unroll
            for (int j=0;j<5;++j) {
                const float4 q = *(const float4*)(Xb + gy*IMG + gx0 + 4*j);
                x[4*j]=q.x; x[4*j+1]=q.y; x[4*j+2]=q.z; x[4*j+3]=q.w;
            }
        } else {
            const float* row = Xb + gy*IMG;
#pragma unroll
            for (int i=0;i<20;++i) {
                const int gx = gx0 + i;
                const float v = row[min(max(gx,0),IMG-1)];
                x[i] = ((unsigned)gx < IMG) ? v : qn;
            }
        }
        // 3-wide running min/max (f32, NaN-ignoring), center x[i+4]
        float mn[12], mx[12];
#pragma unroll
        for (int i=0;i<12;++i) {
            mn[i] = min3f(x[i+3],x[i+4],x[i+5]);
            mx[i] = max3f(x[i+3],x[i+4],x[i+5]);
        }
        unsigned hw[4];
#pragma unroll
        for (int k=0;k<4;++k) {                 // 11-window = m3 at offsets 0,3,6,8
            const float hn = fminf(fminf(mn[k],mn[k+3]), fminf(mn[k+6],mn[k+8]));
            const float hx = fmaxf(fmaxf(mx[k],mx[k+3]), fmaxf(mx[k+6],mx[k+8]));
            UH c; c.h = __builtin_amdgcn_cvt_pkrtz(hn, -hx);   // (min, -max) f16 pair
            hw[k] = c.u;
        }
        *(uint4*)&HNX[wb] = make_uint4(hw[0],hw[1],hw[2],hw[3]);
        if (r >= 2 && r < 40) {                 // gaussH only for rows the v-window uses
            float zz[10];
#pragma unroll
            for (int j=0;j<10;++j) zz[j] = xs ? nan0(x[5+j]) : x[5+j];
            float gh4[4];
#pragma unroll
            for (int k=0;k<4;++k)
                gh4[k] = G0*(zz[k]+zz[k+6]) + G1*(zz[k+1]+zz[k+5]) + G2*(zz[k+2]+zz[k+4]) + G3*zz[k+3];
            *(float4*)&GH[(r-2)*GST+4*g] = make_float4(gh4[0],gh4[1],gh4[2],gh4[3]);
        }
    }

    float a0[4], a1[4];

    // ---- trio (identity + 3x3 cross + pool3) straight from global/L1 ----
    {
        const int gxc = tx0 + xo;
        float L[6], C[6], R[6];
        if (!xe && !ye) {
#pragma unroll
            for (int i=0;i<6;++i) {
                const float* row = Xb + (ty0+y0-1+i)*IMG + gxc;
                L[i]=row[-1]; C[i]=row[0]; R[i]=row[1];
            }
        } else {
#pragma unroll
            for (int i=0;i<6;++i) {
                const int gy = ty0+y0-1+i;
                const bool yv = (unsigned)gy < IMG;
                const float* row = Xb + (yv ? gy : 0)*IMG;
                float l = row[max(gxc-1,0)], c = row[gxc], r = row[min(gxc+1,IMG-1)];
                if (!yv) { l=qn; c=qn; r=qn; }
                if (gxc==0)     l=qn;
                if (gxc==IMG-1) r=qn;
                L[i]=l; C[i]=c; R[i]=r;
            }
        }
        float hm[6], hx6[6];
#pragma unroll
        for (int i=0;i<6;++i) { hm[i]=min3f(L[i],C[i],R[i]); hx6[i]=max3f(L[i],C[i],R[i]); }
        float Lz[6], Rz[6];
#pragma unroll
        for (int i=0;i<6;++i) { Lz[i] = xe ? nan0(L[i]) : L[i];
                                Rz[i] = xe ? nan0(R[i]) : R[i]; }
        const float Cz0 = ye ? nan0(C[0]) : C[0];
        const float Cz5 = ye ? nan0(C[5]) : C[5];
        const float up[4]={Cz0,C[1],C[2],C[3]};
        const float dn[4]={C[2],C[3],C[4],Cz5};
#pragma unroll
        for (int p=0;p<4;++p) {
            const float cr = 0.25f*(up[p] + dn[p] + Lz[p+1] + Rz[p+1]);
            a0[p] = B0 + W0c0*C[p+1] + W1c0*cr;
            a1[p] = B1 + W0c1*C[p+1] + W1c1*cr;
            const float mnv = min3f(hm[p],hm[p+1],hm[p+2]);
            const float mxv = max3f(hx6[p],hx6[p+1],hx6[p+2]);
            a0[p] += W3c0*mnv + W5c0*mxv;
            a1[p] += W3c1*mnv + W5c1*mxv;
        }
    }
    __syncthreads();

    // ---- consumers: batch LDS loads (10 GH + 14 HNX), then compute ----
    {
        float wv[10];
        h2v q[14];
#pragma unroll
        for (int i=0;i<10;++i) wv[i] = GH[(y0+i)*GST+xo];
#pragma unroll
        for (int i=0;i<14;++i) { UH uu; uu.u = HNX[(y0+i)*GST+xo]; q[i] = uu.h; }
        if (ye) {
#pragma unroll
            for (int i=0;i<10;++i) wv[i] = nan0(wv[i]);
        }
        // gaussV
#pragma unroll
        for (int p=0;p<4;++p) {
            const float s = G0*(wv[p]+wv[p+6]) + G1*(wv[p+1]+wv[p+5])
                          + G2*(wv[p+2]+wv[p+4]) + G3*wv[p+3];
            a0[p] += W2c0*s; a1[p] += W2c1*s;
        }
        // v11 van Herk, both chains per packed op (lo=min, hi=-max)
        h2v s = q[10];
#pragma unroll
        for (int i=9;i>=4;--i) s = __builtin_elementwise_min(s, q[i]);
        const h2v S3 = __builtin_elementwise_min(s,  q[3]);
        const h2v S2 = __builtin_elementwise_min(S3, q[2]);
        const h2v S1 = __builtin_elementwise_min(S2, q[1]);
        const h2v S0 = __builtin_elementwise_min(S1, q[0]);
        const h2v p1 = q[11];
        const h2v p2 = __builtin_elementwise_min(p1, q[12]);
        const h2v p3 = __builtin_elementwise_min(p2, q[13]);
        const h2v o0 = S0;
        const h2v o1 = __builtin_elementwise_min(S1, p1);
        const h2v o2 = __builtin_elementwise_min(S2, p2);
        const h2v o3 = __builtin_elementwise_min(S3, p3);
        const float on[4] = {(float)o0[0], (float)o1[0], (float)o2[0], (float)o3[0]};
        const float ox[4] = {-(float)o0[1], -(float)o1[1], -(float)o2[1], -(float)o3[1]};
#pragma unroll
        for (int p=0;p<4;++p) {
            a0[p] += W4c0*on[p] + W6c0*ox[p];
            a1[p] += W4c1*on[p] + W6c1*ox[p];
        }
    }

    float* o0p = out + ((size_t)bz*2 + 0)*(IMG*IMG) + (size_t)(ty0+y0)*IMG + tx0 + xo;
    float* o1p = o0p + (IMG*IMG);
#pragma unroll
    for (int p=0;p<4;++p) {
        o0p[(size_t)p*IMG] = a0[p];
        o1p[(size_t)p*IMG] = a1[p];
    }
}

extern "C" void kernel_launch(void* const* d_in, const int* in_sizes, int n_in,
                              void* d_out, int out_size, void* d_ws, size_t ws_size,
                              hipStream_t stream) {
    const float* X  = (const float*)d_in[0];
    const float* w0 = (const float*)d_in[1];
    const float* b0 = (const float*)d_in[2];
    const float* w1 = (const float*)d_in[3];
    const float* w2 = (const float*)d_in[4];
    const float* w3 = (const float*)d_in[5];
    const float* w4 = (const float*)d_in[6];
    const float* w5 = (const float*)d_in[7];
    const float* w6 = (const float*)d_in[8];
    float* out = (float*)d_out;

    dim3 grid(IMG/TW, IMG/TH, 32);
    simplenet_fused<<<grid, 512, 0, stream>>>(X, w0, b0, w1, w2, w3, w4, w5, w6, out);
}